// Round 2
// baseline (1396.783 us; speedup 1.0000x reference)
//
#include <hip/hip_runtime.h>
#include <hip/hip_bf16.h>
#include <math.h>

#define BLK   256
#define IPT   16
#define TILE  (BLK * IPT)      // 4096
#define BINS  256
#define PASSES 4               // 4 x 8-bit digits

// ---------------- key generation ----------------
__global__ __launch_bounds__(256) void k_keys(const float* __restrict__ pts,
                                              const float* __restrict__ w2v,
                                              int N,
                                              unsigned* __restrict__ keys,
                                              unsigned* __restrict__ idx)
{
    int i = blockIdx.x * 256 + threadIdx.x;
    if (i >= N) return;
    float x = pts[3*i+0], y = pts[3*i+1], z = pts[3*i+2];
    float zv = x*w2v[2] + y*w2v[6] + z*w2v[10] + w2v[14];
    float key = (zv >= 0.2f) ? zv : __int_as_float(0x7f800000); // +inf when culled
    unsigned u = __float_as_uint(key);
    u ^= (u & 0x80000000u) ? 0xFFFFFFFFu : 0x80000000u;        // float -> sortable u32
    keys[i] = u;
    idx[i]  = (unsigned)i;
}

// ---------------- per-tile 256-bin histogram (digit-major output) ----------------
__global__ __launch_bounds__(256) void k_hist8(const unsigned* __restrict__ keys,
                                               int N, int numTiles, int shift,
                                               unsigned* __restrict__ hist)
{
    __shared__ unsigned bins[BINS];
    int t = threadIdx.x, b = blockIdx.x;
    bins[t] = 0;
    __syncthreads();
    int base = b * TILE;
    for (int k = 0; k < IPT; ++k) {
        int l = base + k * BLK + t;
        if (l < N) atomicAdd(&bins[(keys[l] >> shift) & 255u], 1u);
    }
    __syncthreads();
    hist[t * numTiles + b] = bins[t];
}

// ---------------- exclusive scan over hist (E = 256*numTiles) ----------------
__global__ __launch_bounds__(256) void k_scan(unsigned* __restrict__ hist, int E)
{
    __shared__ unsigned sums[256];
    int t = threadIdx.x;
    int per = (E + 255) / 256;
    int s = t * per;
    int e = s + per; if (e > E) e = E; if (s > E) s = E;
    unsigned acc = 0;
    for (int i = s; i < e; ++i) acc += hist[i];
    sums[t] = acc;
    __syncthreads();
    for (int off = 1; off < 256; off <<= 1) {
        unsigned v = (t >= off) ? sums[t - off] : 0u;
        __syncthreads();
        sums[t] += v;
        __syncthreads();
    }
    unsigned run = (t == 0) ? 0u : sums[t - 1];
    for (int i = s; i < e; ++i) { unsigned h = hist[i]; hist[i] = run; run += h; }
}

// ---------------- stable 8-bit rank + scatter (ballot multi-split) ----------------
__global__ __launch_bounds__(256) void k_scatter8(const unsigned* __restrict__ keys,
                                                  const unsigned* __restrict__ vals,
                                                  int N, int numTiles, int shift,
                                                  const unsigned* __restrict__ hist,
                                                  unsigned* __restrict__ okeys,
                                                  unsigned* __restrict__ ovals)
{
    __shared__ unsigned short cnt[64 * BINS];   // [s = it*4 + wave][digit], 32 KB
    __shared__ unsigned tileBase[BINS];

    int t = threadIdx.x, b = blockIdx.x;
    int w = t >> 6, l = t & 63;
    int base = b * TILE;

    // zero counters
    unsigned* c32 = (unsigned*)cnt;
    #pragma unroll
    for (int i = 0; i < (64 * BINS / 2) / BLK; ++i) c32[i * BLK + t] = 0;
    __syncthreads();

    unsigned k_[IPT], v_[IPT];
    unsigned char r_[IPT], d_[IPT];

    #pragma unroll
    for (int it = 0; it < IPT; ++it) {
        int e = base + it * BLK + t;
        bool ok = e < N;
        k_[it] = ok ? keys[e] : 0u;
        v_[it] = ok ? vals[e] : 0u;
    }

    // stable ranking: element order = (it, wave, lane)
    #pragma unroll
    for (int it = 0; it < IPT; ++it) {
        int e = base + it * BLK + t;
        bool ok = e < N;
        unsigned d = (k_[it] >> shift) & 255u;
        unsigned long long mm = __ballot(ok);
        #pragma unroll
        for (int bb = 0; bb < 8; ++bb) {
            unsigned long long bal = __ballot(ok && ((d >> bb) & 1u));
            mm &= ((d >> bb) & 1u) ? bal : ~bal;
        }
        unsigned long long below = mm & ((1ull << l) - 1ull);
        unsigned rk = (unsigned)__popcll(below);
        if (ok && rk == 0)
            cnt[(it * 4 + w) * BINS + d] = (unsigned short)__popcll(mm);
        r_[it] = (unsigned char)rk;
        d_[it] = (unsigned char)d;
    }
    __syncthreads();

    // per-digit exclusive prefix over the 64 wave-iters (thread t owns digit t)
    {
        unsigned run = 0;
        #pragma unroll
        for (int s = 0; s < 64; ++s) {
            unsigned h = cnt[s * BINS + t];
            cnt[s * BINS + t] = (unsigned short)run;
            run += h;
        }
        tileBase[t] = hist[t * numTiles + b];
    }
    __syncthreads();

    #pragma unroll
    for (int it = 0; it < IPT; ++it) {
        int e = base + it * BLK + t;
        if (e >= N) continue;
        unsigned d = d_[it];
        unsigned pos = tileBase[d] + (unsigned)cnt[(it * 4 + w) * BINS + d] + (unsigned)r_[it];
        okeys[pos] = k_[it];
        ovals[pos] = v_[it];
    }
}

// ---------------- per-point math in INPUT order -> padded 24-float rows ----------------
__device__ __forceinline__ void compute_row(int j,
                                            const float* __restrict__ pts,
                                            const float* __restrict__ cols,
                                            const float* __restrict__ opa,
                                            const float* __restrict__ scl,
                                            const float* __restrict__ qt,
                                            const float* __restrict__ w2v,
                                            const float* __restrict__ fpm,
                                            float tanX, float tanY, float fx, float fy,
                                            float Wf, float Hf,
                                            float* r /* 21 floats */)
{
    float x = pts[3*j+0], y = pts[3*j+1], z = pts[3*j+2];

    float qw = qt[4*j+0], qx = qt[4*j+1], qy = qt[4*j+2], qz = qt[4*j+3];
    float qn = sqrtf(qw*qw + qx*qx + qy*qy + qz*qz);
    qw /= qn; qx /= qn; qy /= qn; qz /= qn;
    float R00 = 1.f - 2.f*(qy*qy + qz*qz), R01 = 2.f*(qx*qy - qw*qz), R02 = 2.f*(qx*qz + qw*qy);
    float R10 = 2.f*(qx*qy + qw*qz), R11 = 1.f - 2.f*(qx*qx + qz*qz), R12 = 2.f*(qy*qz - qw*qx);
    float R20 = 2.f*(qx*qz - qw*qy), R21 = 2.f*(qy*qz + qw*qx), R22 = 1.f - 2.f*(qx*qx + qy*qy);

    float s0 = scl[3*j+0], s1 = scl[3*j+1], s2 = scl[3*j+2];
    float M00=R00*s0, M01=R01*s1, M02=R02*s2;
    float M10=R10*s0, M11=R11*s1, M12=R12*s2;
    float M20=R20*s0, M21=R21*s1, M22=R22*s2;
    float C00=M00*M00+M01*M01+M02*M02;
    float C01=M00*M10+M01*M11+M02*M12;
    float C02=M00*M20+M01*M21+M02*M22;
    float C11=M10*M10+M11*M11+M12*M12;
    float C12=M10*M20+M11*M21+M12*M22;
    float C22=M20*M20+M21*M21+M22*M22;

    float pvx = x*w2v[0] + y*w2v[4] + z*w2v[8]  + w2v[12];
    float pvy = x*w2v[1] + y*w2v[5] + z*w2v[9]  + w2v[13];
    float zv  = x*w2v[2] + y*w2v[6] + z*w2v[10] + w2v[14];
    bool in_view = (zv >= 0.2f);

    float cx = x*fpm[0] + y*fpm[4] + z*fpm[8]  + fpm[12];
    float cy = x*fpm[1] + y*fpm[5] + z*fpm[9]  + fpm[13];
    float cw = x*fpm[3] + y*fpm[7] + z*fpm[11] + fpm[15];
    float ndx = cx / cw, ndy = cy / cw;
    float px = ((ndx + 1.f) * Wf - 1.f) * 0.5f;
    float py = ((ndy + 1.f) * Hf - 1.f) * 0.5f;

    float lx = 1.3f * tanX, ly = 1.3f * tanY;
    float xc = fminf(fmaxf(pvx / zv, -lx), lx) * zv;
    float yc = fminf(fmaxf(pvy / zv, -ly), ly) * zv;
    float z2 = zv * zv;
    float J00 = fx / zv, J02 = -(fx * xc) / z2;
    float J11 = fy / zv, J12 = -(fy * yc) / z2;

    float T00 = J00*w2v[0] + J02*w2v[2];
    float T01 = J00*w2v[4] + J02*w2v[6];
    float T02 = J00*w2v[8] + J02*w2v[10];
    float T10 = J11*w2v[1] + J12*w2v[2];
    float T11 = J11*w2v[5] + J12*w2v[6];
    float T12 = J11*w2v[9] + J12*w2v[10];

    float V00 = T00*C00 + T01*C01 + T02*C02;
    float V01 = T00*C01 + T01*C11 + T02*C12;
    float V02 = T00*C02 + T01*C12 + T02*C22;
    float V10 = T10*C00 + T11*C01 + T12*C02;
    float V11 = T10*C01 + T11*C11 + T12*C12;
    float V12 = T10*C02 + T11*C12 + T12*C22;
    float c00 = V00*T00 + V01*T01 + V02*T02;
    float c01 = V00*T10 + V01*T11 + V02*T12;
    float c10 = V10*T00 + V11*T01 + V12*T02;
    float c11 = V10*T10 + V11*T11 + V12*T12;

    float det = c00*c11 - c01*c10;
    float det_safe = (fabsf(det) < 1e-6f) ? 1e-6f : det;
    float i00 =  c11 / det_safe, i01 = -c01 / det_safe;
    float i10 = -c10 / det_safe, i11 =  c00 / det_safe;
    float mid = 0.5f * (c00 + c11);
    float inter = fmaxf(mid*mid - det, 0.1f);
    float lam = mid + sqrtf(inter);
    float radius = ceilf(3.0f * sqrtf(fmaxf(lam, 0.0f)));
    float min_x = floorf(px - radius), min_y = floorf(py - radius);
    float max_x = ceilf(px + radius),  max_y = ceilf(py + radius);
    float op = 1.0f / (1.0f + expf(-opa[j]));

    r[0]=px; r[1]=py; r[2]=zv;
    r[3]=c00; r[4]=c01; r[5]=c10; r[6]=c11;
    r[7]=i00; r[8]=i01; r[9]=i10; r[10]=i11;
    r[11]=radius; r[12]=min_x; r[13]=min_y; r[14]=max_x; r[15]=max_y;
    r[16]=cols[3*j+0]; r[17]=cols[3*j+1]; r[18]=cols[3*j+2];
    r[19]=op; r[20]= in_view ? 1.0f : 0.0f;
}

__global__ __launch_bounds__(256) void k_rows(const float* __restrict__ pts,
                                              const float* __restrict__ cols,
                                              const float* __restrict__ opa,
                                              const float* __restrict__ scl,
                                              const float* __restrict__ qt,
                                              const float* __restrict__ w2v,
                                              const float* __restrict__ fpm,
                                              const float* __restrict__ tanx_p,
                                              const float* __restrict__ tany_p,
                                              const float* __restrict__ fx_p,
                                              const float* __restrict__ fy_p,
                                              const int* __restrict__ wp,
                                              const int* __restrict__ hp,
                                              float* __restrict__ rows, int N)
{
    int i = blockIdx.x * 256 + threadIdx.x;
    if (i >= N) return;
    float r[21];
    compute_row(i, pts, cols, opa, scl, qt, w2v, fpm,
                tanx_p[0], tany_p[0], fx_p[0], fy_p[0],
                (float)wp[0], (float)hp[0], r);
    float4* rp = (float4*)(rows + (size_t)i * 24);
    rp[0] = make_float4(r[0],  r[1],  r[2],  r[3]);
    rp[1] = make_float4(r[4],  r[5],  r[6],  r[7]);
    rp[2] = make_float4(r[8],  r[9],  r[10], r[11]);
    rp[3] = make_float4(r[12], r[13], r[14], r[15]);
    rp[4] = make_float4(r[16], r[17], r[18], r[19]);
    rp[5] = make_float4(r[20], 0.f,   0.f,   0.f);
}

// ---------------- permute padded rows -> compact sorted output ----------------
__global__ __launch_bounds__(256) void k_perm(const unsigned* __restrict__ order,
                                              const float* __restrict__ rows,
                                              float* __restrict__ out, int N)
{
    __shared__ float srow[256 * 21];
    int i = blockIdx.x * 256 + threadIdx.x;
    if (i < N) {
        int j = (int)order[i];
        const float4* rp = (const float4*)(rows + (size_t)j * 24);
        float4 a = rp[0], b4 = rp[1], c4 = rp[2], d4 = rp[3], e4 = rp[4];
        float  f = rows[(size_t)j * 24 + 20];
        float* r = &srow[threadIdx.x * 21];
        r[0]=a.x;  r[1]=a.y;  r[2]=a.z;  r[3]=a.w;
        r[4]=b4.x; r[5]=b4.y; r[6]=b4.z; r[7]=b4.w;
        r[8]=c4.x; r[9]=c4.y; r[10]=c4.z; r[11]=c4.w;
        r[12]=d4.x; r[13]=d4.y; r[14]=d4.z; r[15]=d4.w;
        r[16]=e4.x; r[17]=e4.y; r[18]=e4.z; r[19]=e4.w;
        r[20]=f;
    }
    __syncthreads();
    int blockBase = blockIdx.x * 256;
    int valid = N - blockBase; if (valid > 256) valid = 256;
    if (valid > 0) {
        float* dst = out + (size_t)blockBase * 21;
        for (int u = threadIdx.x; u < valid * 21; u += 256) dst[u] = srow[u];
    }
}

// ---------------- fallback: fused gather+math in sorted order ----------------
__global__ __launch_bounds__(256) void k_emit(const unsigned* __restrict__ order,
                                              const float* __restrict__ pts,
                                              const float* __restrict__ cols,
                                              const float* __restrict__ opa,
                                              const float* __restrict__ scl,
                                              const float* __restrict__ qt,
                                              const float* __restrict__ w2v,
                                              const float* __restrict__ fpm,
                                              const float* __restrict__ tanx_p,
                                              const float* __restrict__ tany_p,
                                              const float* __restrict__ fx_p,
                                              const float* __restrict__ fy_p,
                                              const int* __restrict__ wp,
                                              const int* __restrict__ hp,
                                              float* __restrict__ out, int N)
{
    __shared__ float srow[256 * 21];
    int i = blockIdx.x * 256 + threadIdx.x;
    if (i < N) {
        int j = (int)order[i];
        compute_row(j, pts, cols, opa, scl, qt, w2v, fpm,
                    tanx_p[0], tany_p[0], fx_p[0], fy_p[0],
                    (float)wp[0], (float)hp[0], &srow[threadIdx.x * 21]);
    }
    __syncthreads();
    int blockBase = blockIdx.x * 256;
    int valid = N - blockBase; if (valid > 256) valid = 256;
    if (valid > 0) {
        float* dst = out + (size_t)blockBase * 21;
        for (int u = threadIdx.x; u < valid * 21; u += 256) dst[u] = srow[u];
    }
}

extern "C" void kernel_launch(void* const* d_in, const int* in_sizes, int n_in,
                              void* d_out, int out_size, void* d_ws, size_t ws_size,
                              hipStream_t stream)
{
    const float* pts  = (const float*)d_in[0];
    const float* cols = (const float*)d_in[1];
    const float* opa  = (const float*)d_in[2];
    const float* scl  = (const float*)d_in[3];
    const float* qt   = (const float*)d_in[4];
    const float* w2v  = (const float*)d_in[5];
    const float* fpm  = (const float*)d_in[6];
    const float* tanx = (const float*)d_in[7];
    const float* tany = (const float*)d_in[8];
    const float* fx   = (const float*)d_in[9];
    const float* fy   = (const float*)d_in[10];
    const int*   wp   = (const int*)d_in[11];
    const int*   hp   = (const int*)d_in[12];

    int N = in_sizes[0] / 3;
    int numTiles = (N + TILE - 1) / TILE;
    int nb = (N + 255) / 256;

    unsigned* keysA = (unsigned*)d_ws;
    unsigned* idxA  = keysA + N;
    unsigned* keysB = idxA  + N;
    unsigned* idxB  = keysB + N;
    unsigned* hist  = idxB  + N;                       // BINS * numTiles
    float*    rows  = (float*)(hist + (size_t)BINS * numTiles);

    size_t need = ((size_t)4 * N + (size_t)BINS * numTiles) * 4 + (size_t)N * 24 * 4;
    bool split = (ws_size >= need);

    k_keys<<<nb, 256, 0, stream>>>(pts, w2v, N, keysA, idxA);

    unsigned *ck = keysA, *cv = idxA, *nk = keysB, *nvv = idxB;
    for (int p = 0; p < PASSES; ++p) {
        int shift = p * 8;
        k_hist8<<<numTiles, 256, 0, stream>>>(ck, N, numTiles, shift, hist);
        k_scan<<<1, 256, 0, stream>>>(hist, BINS * numTiles);
        k_scatter8<<<numTiles, 256, 0, stream>>>(ck, cv, N, numTiles, shift, hist, nk, nvv);
        unsigned* tk = ck; ck = nk; nk = tk;
        unsigned* tv = cv; cv = nvv; nvv = tv;
    }

    if (split) {
        k_rows<<<nb, 256, 0, stream>>>(pts, cols, opa, scl, qt, w2v, fpm,
                                       tanx, tany, fx, fy, wp, hp, rows, N);
        k_perm<<<nb, 256, 0, stream>>>(cv, rows, (float*)d_out, N);
    } else {
        k_emit<<<nb, 256, 0, stream>>>(cv, pts, cols, opa, scl, qt, w2v, fpm,
                                       tanx, tany, fx, fy, wp, hp,
                                       (float*)d_out, N);
    }
}

// Round 3
// 562.225 us; speedup vs baseline: 2.4844x; 2.4844x over previous
//
#include <hip/hip_runtime.h>
#include <hip/hip_bf16.h>
#include <math.h>

#define BLK   256
#define IPT   16
#define TILE  (BLK * IPT)      // 4096
#define BINS  256
#define PASSES 4               // 4 x 8-bit digits
#define SCT   4096             // scan chunk

// ---------------- key generation ----------------
__global__ __launch_bounds__(256) void k_keys(const float* __restrict__ pts,
                                              const float* __restrict__ w2v,
                                              int N,
                                              unsigned* __restrict__ keys,
                                              unsigned* __restrict__ idx)
{
    int i = blockIdx.x * 256 + threadIdx.x;
    if (i >= N) return;
    float x = pts[3*i+0], y = pts[3*i+1], z = pts[3*i+2];
    float zv = x*w2v[2] + y*w2v[6] + z*w2v[10] + w2v[14];
    float key = (zv >= 0.2f) ? zv : __int_as_float(0x7f800000); // +inf when culled
    unsigned u = __float_as_uint(key);
    u ^= (u & 0x80000000u) ? 0xFFFFFFFFu : 0x80000000u;        // float -> sortable u32
    keys[i] = u;
    idx[i]  = (unsigned)i;
}

// ---------------- per-tile 256-bin histogram (digit-major output) ----------------
__global__ __launch_bounds__(256) void k_hist8(const unsigned* __restrict__ keys,
                                               int N, int numTiles, int shift,
                                               unsigned* __restrict__ hist)
{
    __shared__ unsigned bins[BINS];
    int t = threadIdx.x, b = blockIdx.x;
    bins[t] = 0;
    __syncthreads();
    int base = b * TILE;
    for (int k = 0; k < IPT; ++k) {
        int l = base + k * BLK + t;
        if (l < N) atomicAdd(&bins[(keys[l] >> shift) & 255u], 1u);
    }
    __syncthreads();
    hist[t * numTiles + b] = bins[t];
}

// ---------------- hierarchical exclusive scan over hist ----------------
// A: per-chunk reduction
__global__ __launch_bounds__(256) void k_scanA(const unsigned* __restrict__ h, int E,
                                               unsigned* __restrict__ bsum)
{
    __shared__ unsigned red[256];
    int t = threadIdx.x;
    int base = blockIdx.x * SCT + t * 16;
    unsigned acc = 0;
    if (base + 16 <= E) {
        const uint4* p = (const uint4*)(h + base);
        #pragma unroll
        for (int q = 0; q < 4; ++q) { uint4 v = p[q]; acc += v.x + v.y + v.z + v.w; }
    } else {
        for (int k = 0; k < 16; ++k) { int i = base + k; if (i < E) acc += h[i]; }
    }
    red[t] = acc;
    __syncthreads();
    for (int off = 128; off > 0; off >>= 1) {
        if (t < off) red[t] += red[t + off];
        __syncthreads();
    }
    if (t == 0) bsum[blockIdx.x] = red[0];
}

// B: per-chunk exclusive scan in place, offset by sum of preceding chunk totals
__global__ __launch_bounds__(256) void k_scanB(unsigned* __restrict__ h, int E,
                                               const unsigned* __restrict__ bsum)
{
    __shared__ unsigned tsum[256];
    __shared__ unsigned boff_s;
    int t = threadIdx.x, b = blockIdx.x;
    int base = b * SCT + t * 16;

    if (t == 0) { unsigned o = 0; for (int i = 0; i < b; ++i) o += bsum[i]; boff_s = o; }

    unsigned v[16];
    bool full = (base + 16 <= E);
    if (full) {
        const uint4* p = (const uint4*)(h + base);
        #pragma unroll
        for (int q = 0; q < 4; ++q) { uint4 u = p[q]; v[4*q]=u.x; v[4*q+1]=u.y; v[4*q+2]=u.z; v[4*q+3]=u.w; }
    } else {
        for (int k = 0; k < 16; ++k) { int i = base + k; v[k] = (i < E) ? h[i] : 0u; }
    }
    unsigned acc = 0;
    #pragma unroll
    for (int k = 0; k < 16; ++k) { unsigned x = v[k]; v[k] = acc; acc += x; }
    tsum[t] = acc;
    __syncthreads();
    for (int off = 1; off < 256; off <<= 1) {
        unsigned u = (t >= off) ? tsum[t - off] : 0u;
        __syncthreads();
        tsum[t] += u;
        __syncthreads();
    }
    unsigned add = boff_s + ((t == 0) ? 0u : tsum[t - 1]);
    if (full) {
        uint4* p = (uint4*)(h + base);
        #pragma unroll
        for (int q = 0; q < 4; ++q)
            p[q] = make_uint4(v[4*q] + add, v[4*q+1] + add, v[4*q+2] + add, v[4*q+3] + add);
    } else {
        for (int k = 0; k < 16; ++k) { int i = base + k; if (i < E) h[i] = v[k] + add; }
    }
}

// ---------------- stable 8-bit rank + LDS-staged scatter ----------------
__global__ __launch_bounds__(256) void k_scatter8(const unsigned* __restrict__ keys,
                                                  const unsigned* __restrict__ vals,
                                                  int N, int numTiles, int shift,
                                                  const unsigned* __restrict__ hist,
                                                  unsigned* __restrict__ okeys,
                                                  unsigned* __restrict__ ovals)
{
    __shared__ unsigned short cnt[64 * BINS];   // [s = it*4 + wave][digit], 32 KB
    __shared__ unsigned tileBase[BINS];
    __shared__ unsigned digStartL[BINS];
    __shared__ unsigned tscan[BINS];
    __shared__ unsigned stage_k[TILE];          // 16 KB
    __shared__ unsigned stage_v[TILE];          // 16 KB

    int t = threadIdx.x, b = blockIdx.x;
    int w = t >> 6, l = t & 63;
    int base = b * TILE;
    int nvalid = N - base; if (nvalid < 0) nvalid = 0; if (nvalid > TILE) nvalid = TILE;

    // zero counters
    unsigned* c32 = (unsigned*)cnt;
    #pragma unroll
    for (int i = 0; i < (64 * BINS / 2) / BLK; ++i) c32[i * BLK + t] = 0;
    __syncthreads();

    unsigned k_[IPT], v_[IPT];
    unsigned char r_[IPT], d_[IPT];

    #pragma unroll
    for (int it = 0; it < IPT; ++it) {
        int e = base + it * BLK + t;
        bool ok = e < N;
        k_[it] = ok ? keys[e] : 0u;
        v_[it] = ok ? vals[e] : 0u;
    }

    // stable ranking: element order = (it, wave, lane)
    #pragma unroll
    for (int it = 0; it < IPT; ++it) {
        int e = base + it * BLK + t;
        bool ok = e < N;
        unsigned d = (k_[it] >> shift) & 255u;
        unsigned long long mm = __ballot(ok);
        #pragma unroll
        for (int bb = 0; bb < 8; ++bb) {
            unsigned long long bal = __ballot(ok && ((d >> bb) & 1u));
            mm &= ((d >> bb) & 1u) ? bal : ~bal;
        }
        unsigned long long below = mm & ((1ull << l) - 1ull);
        unsigned rk = (unsigned)__popcll(below);
        if (ok && rk == 0)
            cnt[(it * 4 + w) * BINS + d] = (unsigned short)__popcll(mm);
        r_[it] = (unsigned char)rk;
        d_[it] = (unsigned char)d;
    }
    __syncthreads();

    // per-digit exclusive prefix over the 64 wave-iter segments (thread t owns digit t)
    {
        unsigned run = 0;
        #pragma unroll
        for (int s = 0; s < 64; ++s) {
            unsigned h = cnt[s * BINS + t];
            cnt[s * BINS + t] = (unsigned short)run;
            run += h;
        }
        tscan[t] = run;                 // digit total for this tile
        tileBase[t] = hist[t * numTiles + b];
    }
    __syncthreads();

    // exclusive scan of digit totals -> local digit start
    for (int off = 1; off < 256; off <<= 1) {
        unsigned u = (t >= off) ? tscan[t - off] : 0u;
        __syncthreads();
        tscan[t] += u;
        __syncthreads();
    }
    digStartL[t] = (t == 0) ? 0u : tscan[t - 1];
    __syncthreads();

    // stage into LDS in tile-sorted order
    #pragma unroll
    for (int it = 0; it < IPT; ++it) {
        int e = base + it * BLK + t;
        if (e >= N) continue;
        unsigned d = d_[it];
        unsigned lp = digStartL[d] + (unsigned)cnt[(it * 4 + w) * BINS + d] + (unsigned)r_[it];
        stage_k[lp] = k_[it];
        stage_v[lp] = v_[it];
    }
    __syncthreads();

    // linear read-back -> coalesced per-digit-run global writes
    #pragma unroll
    for (int it = 0; it < IPT; ++it) {
        int p = it * BLK + t;
        if (p >= nvalid) continue;
        unsigned kk = stage_k[p];
        unsigned d = (kk >> shift) & 255u;
        unsigned pos = tileBase[d] + ((unsigned)p - digStartL[d]);
        okeys[pos] = kk;
        ovals[pos] = stage_v[p];
    }
}

// ---------------- per-point math ----------------
__device__ __forceinline__ void compute_row(int j,
                                            const float* __restrict__ pts,
                                            const float* __restrict__ cols,
                                            const float* __restrict__ opa,
                                            const float* __restrict__ scl,
                                            const float* __restrict__ qt,
                                            const float* __restrict__ w2v,
                                            const float* __restrict__ fpm,
                                            float tanX, float tanY, float fx, float fy,
                                            float Wf, float Hf,
                                            float* r /* 21 floats */)
{
    float x = pts[3*j+0], y = pts[3*j+1], z = pts[3*j+2];

    float qw = qt[4*j+0], qx = qt[4*j+1], qy = qt[4*j+2], qz = qt[4*j+3];
    float qn = sqrtf(qw*qw + qx*qx + qy*qy + qz*qz);
    qw /= qn; qx /= qn; qy /= qn; qz /= qn;
    float R00 = 1.f - 2.f*(qy*qy + qz*qz), R01 = 2.f*(qx*qy - qw*qz), R02 = 2.f*(qx*qz + qw*qy);
    float R10 = 2.f*(qx*qy + qw*qz), R11 = 1.f - 2.f*(qx*qx + qz*qz), R12 = 2.f*(qy*qz - qw*qx);
    float R20 = 2.f*(qx*qz - qw*qy), R21 = 2.f*(qy*qz + qw*qx), R22 = 1.f - 2.f*(qx*qx + qy*qy);

    float s0 = scl[3*j+0], s1 = scl[3*j+1], s2 = scl[3*j+2];
    float M00=R00*s0, M01=R01*s1, M02=R02*s2;
    float M10=R10*s0, M11=R11*s1, M12=R12*s2;
    float M20=R20*s0, M21=R21*s1, M22=R22*s2;
    float C00=M00*M00+M01*M01+M02*M02;
    float C01=M00*M10+M01*M11+M02*M12;
    float C02=M00*M20+M01*M21+M02*M22;
    float C11=M10*M10+M11*M11+M12*M12;
    float C12=M10*M20+M11*M21+M12*M22;
    float C22=M20*M20+M21*M21+M22*M22;

    float pvx = x*w2v[0] + y*w2v[4] + z*w2v[8]  + w2v[12];
    float pvy = x*w2v[1] + y*w2v[5] + z*w2v[9]  + w2v[13];
    float zv  = x*w2v[2] + y*w2v[6] + z*w2v[10] + w2v[14];
    bool in_view = (zv >= 0.2f);

    float cx = x*fpm[0] + y*fpm[4] + z*fpm[8]  + fpm[12];
    float cy = x*fpm[1] + y*fpm[5] + z*fpm[9]  + fpm[13];
    float cw = x*fpm[3] + y*fpm[7] + z*fpm[11] + fpm[15];
    float ndx = cx / cw, ndy = cy / cw;
    float px = ((ndx + 1.f) * Wf - 1.f) * 0.5f;
    float py = ((ndy + 1.f) * Hf - 1.f) * 0.5f;

    float lx = 1.3f * tanX, ly = 1.3f * tanY;
    float xc = fminf(fmaxf(pvx / zv, -lx), lx) * zv;
    float yc = fminf(fmaxf(pvy / zv, -ly), ly) * zv;
    float z2 = zv * zv;
    float J00 = fx / zv, J02 = -(fx * xc) / z2;
    float J11 = fy / zv, J12 = -(fy * yc) / z2;

    float T00 = J00*w2v[0] + J02*w2v[2];
    float T01 = J00*w2v[4] + J02*w2v[6];
    float T02 = J00*w2v[8] + J02*w2v[10];
    float T10 = J11*w2v[1] + J12*w2v[2];
    float T11 = J11*w2v[5] + J12*w2v[6];
    float T12 = J11*w2v[9] + J12*w2v[10];

    float V00 = T00*C00 + T01*C01 + T02*C02;
    float V01 = T00*C01 + T01*C11 + T02*C12;
    float V02 = T00*C02 + T01*C12 + T02*C22;
    float V10 = T10*C00 + T11*C01 + T12*C02;
    float V11 = T10*C01 + T11*C11 + T12*C12;
    float V12 = T10*C02 + T11*C12 + T12*C22;
    float c00 = V00*T00 + V01*T01 + V02*T02;
    float c01 = V00*T10 + V01*T11 + V02*T12;
    float c10 = V10*T00 + V11*T01 + V12*T02;
    float c11 = V10*T10 + V11*T11 + V12*T12;

    float det = c00*c11 - c01*c10;
    float det_safe = (fabsf(det) < 1e-6f) ? 1e-6f : det;
    float i00 =  c11 / det_safe, i01 = -c01 / det_safe;
    float i10 = -c10 / det_safe, i11 =  c00 / det_safe;
    float mid = 0.5f * (c00 + c11);
    float inter = fmaxf(mid*mid - det, 0.1f);
    float lam = mid + sqrtf(inter);
    float radius = ceilf(3.0f * sqrtf(fmaxf(lam, 0.0f)));
    float min_x = floorf(px - radius), min_y = floorf(py - radius);
    float max_x = ceilf(px + radius),  max_y = ceilf(py + radius);
    float op = 1.0f / (1.0f + expf(-opa[j]));

    r[0]=px; r[1]=py; r[2]=zv;
    r[3]=c00; r[4]=c01; r[5]=c10; r[6]=c11;
    r[7]=i00; r[8]=i01; r[9]=i10; r[10]=i11;
    r[11]=radius; r[12]=min_x; r[13]=min_y; r[14]=max_x; r[15]=max_y;
    r[16]=cols[3*j+0]; r[17]=cols[3*j+1]; r[18]=cols[3*j+2];
    r[19]=op; r[20]= in_view ? 1.0f : 0.0f;
}

__global__ __launch_bounds__(256) void k_rows(const float* __restrict__ pts,
                                              const float* __restrict__ cols,
                                              const float* __restrict__ opa,
                                              const float* __restrict__ scl,
                                              const float* __restrict__ qt,
                                              const float* __restrict__ w2v,
                                              const float* __restrict__ fpm,
                                              const float* __restrict__ tanx_p,
                                              const float* __restrict__ tany_p,
                                              const float* __restrict__ fx_p,
                                              const float* __restrict__ fy_p,
                                              const int* __restrict__ wp,
                                              const int* __restrict__ hp,
                                              float* __restrict__ rows, int N)
{
    int i = blockIdx.x * 256 + threadIdx.x;
    if (i >= N) return;
    float r[21];
    compute_row(i, pts, cols, opa, scl, qt, w2v, fpm,
                tanx_p[0], tany_p[0], fx_p[0], fy_p[0],
                (float)wp[0], (float)hp[0], r);
    float4* rp = (float4*)(rows + (size_t)i * 24);
    rp[0] = make_float4(r[0],  r[1],  r[2],  r[3]);
    rp[1] = make_float4(r[4],  r[5],  r[6],  r[7]);
    rp[2] = make_float4(r[8],  r[9],  r[10], r[11]);
    rp[3] = make_float4(r[12], r[13], r[14], r[15]);
    rp[4] = make_float4(r[16], r[17], r[18], r[19]);
    rp[5] = make_float4(r[20], 0.f,   0.f,   0.f);
}

// ---------------- permute padded rows -> compact sorted output ----------------
__global__ __launch_bounds__(256) void k_perm(const unsigned* __restrict__ order,
                                              const float* __restrict__ rows,
                                              float* __restrict__ out, int N)
{
    __shared__ float srow[256 * 21];
    int i = blockIdx.x * 256 + threadIdx.x;
    if (i < N) {
        int j = (int)order[i];
        const float4* rp = (const float4*)(rows + (size_t)j * 24);
        float4 a = rp[0], b4 = rp[1], c4 = rp[2], d4 = rp[3], e4 = rp[4];
        float  f = rows[(size_t)j * 24 + 20];
        float* r = &srow[threadIdx.x * 21];
        r[0]=a.x;  r[1]=a.y;  r[2]=a.z;  r[3]=a.w;
        r[4]=b4.x; r[5]=b4.y; r[6]=b4.z; r[7]=b4.w;
        r[8]=c4.x; r[9]=c4.y; r[10]=c4.z; r[11]=c4.w;
        r[12]=d4.x; r[13]=d4.y; r[14]=d4.z; r[15]=d4.w;
        r[16]=e4.x; r[17]=e4.y; r[18]=e4.z; r[19]=e4.w;
        r[20]=f;
    }
    __syncthreads();
    int blockBase = blockIdx.x * 256;
    int valid = N - blockBase; if (valid > 256) valid = 256;
    if (valid > 0) {
        float* dst = out + (size_t)blockBase * 21;
        for (int u = threadIdx.x; u < valid * 21; u += 256) dst[u] = srow[u];
    }
}

// ---------------- fallback: fused gather+math in sorted order ----------------
__global__ __launch_bounds__(256) void k_emit(const unsigned* __restrict__ order,
                                              const float* __restrict__ pts,
                                              const float* __restrict__ cols,
                                              const float* __restrict__ opa,
                                              const float* __restrict__ scl,
                                              const float* __restrict__ qt,
                                              const float* __restrict__ w2v,
                                              const float* __restrict__ fpm,
                                              const float* __restrict__ tanx_p,
                                              const float* __restrict__ tany_p,
                                              const float* __restrict__ fx_p,
                                              const float* __restrict__ fy_p,
                                              const int* __restrict__ wp,
                                              const int* __restrict__ hp,
                                              float* __restrict__ out, int N)
{
    __shared__ float srow[256 * 21];
    int i = blockIdx.x * 256 + threadIdx.x;
    if (i < N) {
        int j = (int)order[i];
        compute_row(j, pts, cols, opa, scl, qt, w2v, fpm,
                    tanx_p[0], tany_p[0], fx_p[0], fy_p[0],
                    (float)wp[0], (float)hp[0], &srow[threadIdx.x * 21]);
    }
    __syncthreads();
    int blockBase = blockIdx.x * 256;
    int valid = N - blockBase; if (valid > 256) valid = 256;
    if (valid > 0) {
        float* dst = out + (size_t)blockBase * 21;
        for (int u = threadIdx.x; u < valid * 21; u += 256) dst[u] = srow[u];
    }
}

extern "C" void kernel_launch(void* const* d_in, const int* in_sizes, int n_in,
                              void* d_out, int out_size, void* d_ws, size_t ws_size,
                              hipStream_t stream)
{
    const float* pts  = (const float*)d_in[0];
    const float* cols = (const float*)d_in[1];
    const float* opa  = (const float*)d_in[2];
    const float* scl  = (const float*)d_in[3];
    const float* qt   = (const float*)d_in[4];
    const float* w2v  = (const float*)d_in[5];
    const float* fpm  = (const float*)d_in[6];
    const float* tanx = (const float*)d_in[7];
    const float* tany = (const float*)d_in[8];
    const float* fx   = (const float*)d_in[9];
    const float* fy   = (const float*)d_in[10];
    const int*   wp   = (const int*)d_in[11];
    const int*   hp   = (const int*)d_in[12];

    int N = in_sizes[0] / 3;
    int numTiles = (N + TILE - 1) / TILE;
    int nb = (N + 255) / 256;
    int E = BINS * numTiles;
    int nScan = (E + SCT - 1) / SCT;

    unsigned* keysA = (unsigned*)d_ws;
    unsigned* idxA  = keysA + N;
    unsigned* keysB = idxA  + N;
    unsigned* idxB  = keysB + N;
    unsigned* hist  = idxB  + N;                       // E entries
    unsigned* bsum  = hist + E;                        // nScan entries
    float*    rows  = (float*)(bsum + nScan);

    size_t need = ((size_t)4 * N + E + nScan) * 4 + (size_t)N * 24 * 4;
    bool split = (ws_size >= need);

    k_keys<<<nb, 256, 0, stream>>>(pts, w2v, N, keysA, idxA);

    unsigned *ck = keysA, *cv = idxA, *nk = keysB, *nvv = idxB;
    for (int p = 0; p < PASSES; ++p) {
        int shift = p * 8;
        k_hist8<<<numTiles, 256, 0, stream>>>(ck, N, numTiles, shift, hist);
        k_scanA<<<nScan, 256, 0, stream>>>(hist, E, bsum);
        k_scanB<<<nScan, 256, 0, stream>>>(hist, E, bsum);
        k_scatter8<<<numTiles, 256, 0, stream>>>(ck, cv, N, numTiles, shift, hist, nk, nvv);
        unsigned* tk = ck; ck = nk; nk = tk;
        unsigned* tv = cv; cv = nvv; nvv = tv;
    }

    if (split) {
        k_rows<<<nb, 256, 0, stream>>>(pts, cols, opa, scl, qt, w2v, fpm,
                                       tanx, tany, fx, fy, wp, hp, rows, N);
        k_perm<<<nb, 256, 0, stream>>>(cv, rows, (float*)d_out, N);
    } else {
        k_emit<<<nb, 256, 0, stream>>>(cv, pts, cols, opa, scl, qt, w2v, fpm,
                                       tanx, tany, fx, fy, wp, hp,
                                       (float*)d_out, N);
    }
}

// Round 4
// 503.450 us; speedup vs baseline: 2.7744x; 1.1167x over previous
//
#include <hip/hip_runtime.h>
#include <hip/hip_bf16.h>
#include <math.h>

#define BLK   256
#define IPT   16
#define TILE  (BLK * IPT)      // 4096
#define CHUNK 1024             // per-wave contiguous chunk inside a tile
#define BINS  256
#define PASSES 4               // 4 x 8-bit digits
#define SCT   4096             // scan chunk

// ---------------- per-point math + key gen, input order -> 16-float rows ----------------
__global__ __launch_bounds__(256) void k_rows(const float* __restrict__ pts,
                                              const float* __restrict__ cols,
                                              const float* __restrict__ opa,
                                              const float* __restrict__ scl,
                                              const float* __restrict__ qt,
                                              const float* __restrict__ w2v,
                                              const float* __restrict__ fpm,
                                              const float* __restrict__ tanx_p,
                                              const float* __restrict__ tany_p,
                                              const float* __restrict__ fx_p,
                                              const float* __restrict__ fy_p,
                                              const int* __restrict__ wp,
                                              const int* __restrict__ hp,
                                              float* __restrict__ rows,
                                              unsigned* __restrict__ keys,
                                              int N)
{
    int i = blockIdx.x * 256 + threadIdx.x;
    if (i >= N) return;

    float x = pts[3*i+0], y = pts[3*i+1], z = pts[3*i+2];

    // depth key: zv = x*0 + y*0 + z*1 + 5 -> fl(z+5) exactly, matches numpy bitwise
    float zv = x*w2v[2] + y*w2v[6] + z*w2v[10] + w2v[14];
    bool in_view = (zv >= 0.2f);
    {
        float key = in_view ? zv : __int_as_float(0x7f800000);
        unsigned u = __float_as_uint(key);
        u ^= (u & 0x80000000u) ? 0xFFFFFFFFu : 0x80000000u;   // float -> sortable u32
        keys[i] = u;
    }

    // quaternion -> rotation (rsqrt instead of 4 divides; rel err ~1e-7, threshold 4e11)
    float4 q4 = *(const float4*)(qt + 4*i);
    float qw = q4.x, qx = q4.y, qy = q4.z, qz = q4.w;
    float rn = __builtin_amdgcn_rsqf(qw*qw + qx*qx + qy*qy + qz*qz);
    qw *= rn; qx *= rn; qy *= rn; qz *= rn;
    float R00 = 1.f - 2.f*(qy*qy + qz*qz), R01 = 2.f*(qx*qy - qw*qz), R02 = 2.f*(qx*qz + qw*qy);
    float R10 = 2.f*(qx*qy + qw*qz), R11 = 1.f - 2.f*(qx*qx + qz*qz), R12 = 2.f*(qy*qz - qw*qx);
    float R20 = 2.f*(qx*qz - qw*qy), R21 = 2.f*(qy*qz + qw*qx), R22 = 1.f - 2.f*(qx*qx + qy*qy);

    float s0 = scl[3*i+0], s1 = scl[3*i+1], s2 = scl[3*i+2];
    float M00=R00*s0, M01=R01*s1, M02=R02*s2;
    float M10=R10*s0, M11=R11*s1, M12=R12*s2;
    float M20=R20*s0, M21=R21*s1, M22=R22*s2;
    float C00=M00*M00+M01*M01+M02*M02;
    float C01=M00*M10+M01*M11+M02*M12;
    float C02=M00*M20+M01*M21+M02*M22;
    float C11=M10*M10+M11*M11+M12*M12;
    float C12=M10*M20+M11*M21+M12*M22;
    float C22=M20*M20+M21*M21+M22*M22;

    float pvx = x*w2v[0] + y*w2v[4] + z*w2v[8]  + w2v[12];
    float pvy = x*w2v[1] + y*w2v[5] + z*w2v[9]  + w2v[13];

    float cx = x*fpm[0] + y*fpm[4] + z*fpm[8]  + fpm[12];
    float cy = x*fpm[1] + y*fpm[5] + z*fpm[9]  + fpm[13];
    float cw = x*fpm[3] + y*fpm[7] + z*fpm[11] + fpm[15];
    float rcw = __builtin_amdgcn_rcpf(cw);
    float Wf = (float)wp[0], Hf = (float)hp[0];
    float px = ((cx*rcw + 1.f) * Wf - 1.f) * 0.5f;
    float py = ((cy*rcw + 1.f) * Hf - 1.f) * 0.5f;

    float tanX = tanx_p[0], tanY = tany_p[0], fx = fx_p[0], fy = fy_p[0];
    float lx = 1.3f * tanX, ly = 1.3f * tanY;
    float rzv = __builtin_amdgcn_rcpf(zv);
    float xc = fminf(fmaxf(pvx*rzv, -lx), lx) * zv;
    float yc = fminf(fmaxf(pvy*rzv, -ly), ly) * zv;
    float rz2 = rzv * rzv;
    float J00 = fx * rzv, J02 = -(fx * xc) * rz2;
    float J11 = fy * rzv, J12 = -(fy * yc) * rz2;

    float T00 = J00*w2v[0] + J02*w2v[2];
    float T01 = J00*w2v[4] + J02*w2v[6];
    float T02 = J00*w2v[8] + J02*w2v[10];
    float T10 = J11*w2v[1] + J12*w2v[2];
    float T11 = J11*w2v[5] + J12*w2v[6];
    float T12 = J11*w2v[9] + J12*w2v[10];

    float V00 = T00*C00 + T01*C01 + T02*C02;
    float V01 = T00*C01 + T01*C11 + T02*C12;
    float V02 = T00*C02 + T01*C12 + T02*C22;
    float V10 = T10*C00 + T11*C01 + T12*C02;
    float V11 = T10*C01 + T11*C11 + T12*C12;
    float V12 = T10*C02 + T11*C12 + T12*C22;
    float c00 = V00*T00 + V01*T01 + V02*T02;
    float c01 = V00*T10 + V01*T11 + V02*T12;
    float c10 = V10*T00 + V11*T01 + V12*T02;
    float c11 = V10*T10 + V11*T11 + V12*T12;

    float det = c00*c11 - c01*c10;
    float det_safe = (fabsf(det) < 1e-6f) ? 1e-6f : det;
    float rdet = __builtin_amdgcn_rcpf(det_safe);
    float i00 =  c11 * rdet, i01 = -c01 * rdet, i11 = c00 * rdet;
    float mid = 0.5f * (c00 + c11);
    float inter = fmaxf(mid*mid - det, 0.1f);
    float lam = mid + sqrtf(inter);
    float radius = ceilf(3.0f * sqrtf(fmaxf(lam, 0.0f)));
    float op = __builtin_amdgcn_rcpf(1.0f + __expf(-opa[i]));

    float cr = cols[3*i+0], cg = cols[3*i+1], cb = cols[3*i+2];

    float4* rp = (float4*)(rows + (size_t)i * 16);
    rp[0] = make_float4(px,  py,  zv,  c00);
    rp[1] = make_float4(c01, c11, i00, i01);
    rp[2] = make_float4(i11, radius, cr, cg);
    rp[3] = make_float4(cb,  op,  in_view ? 1.0f : 0.0f, 0.f);
}

// ---------------- per-tile 256-bin histogram, wave-privatized ----------------
__global__ __launch_bounds__(256) void k_hist8(const unsigned* __restrict__ keys,
                                               int N, int numTiles, int shift,
                                               unsigned* __restrict__ hist)
{
    __shared__ unsigned hb[4][BINS];   // 4 KB
    int t = threadIdx.x, b = blockIdx.x, w = t >> 6;
    hb[0][t] = 0; hb[1][t] = 0; hb[2][t] = 0; hb[3][t] = 0;
    __syncthreads();
    int base = b * TILE + t * 16;
    if (base + 16 <= N) {
        const uint4* p = (const uint4*)(keys + base);
        #pragma unroll
        for (int q = 0; q < 4; ++q) {
            uint4 v = p[q];
            atomicAdd(&hb[w][(v.x >> shift) & 255u], 1u);
            atomicAdd(&hb[w][(v.y >> shift) & 255u], 1u);
            atomicAdd(&hb[w][(v.z >> shift) & 255u], 1u);
            atomicAdd(&hb[w][(v.w >> shift) & 255u], 1u);
        }
    } else {
        for (int k = 0; k < 16; ++k) {
            int i = base + k;
            if (i < N) atomicAdd(&hb[w][(keys[i] >> shift) & 255u], 1u);
        }
    }
    __syncthreads();
    hist[t * numTiles + b] = hb[0][t] + hb[1][t] + hb[2][t] + hb[3][t];
}

// ---------------- hierarchical exclusive scan over hist ----------------
__global__ __launch_bounds__(256) void k_scanA(const unsigned* __restrict__ h, int E,
                                               unsigned* __restrict__ bsum)
{
    __shared__ unsigned red[256];
    int t = threadIdx.x;
    int base = blockIdx.x * SCT + t * 16;
    unsigned acc = 0;
    if (base + 16 <= E) {
        const uint4* p = (const uint4*)(h + base);
        #pragma unroll
        for (int q = 0; q < 4; ++q) { uint4 v = p[q]; acc += v.x + v.y + v.z + v.w; }
    } else {
        for (int k = 0; k < 16; ++k) { int i = base + k; if (i < E) acc += h[i]; }
    }
    red[t] = acc;
    __syncthreads();
    for (int off = 128; off > 0; off >>= 1) {
        if (t < off) red[t] += red[t + off];
        __syncthreads();
    }
    if (t == 0) bsum[blockIdx.x] = red[0];
}

__global__ __launch_bounds__(256) void k_scanB(unsigned* __restrict__ h, int E,
                                               const unsigned* __restrict__ bsum)
{
    __shared__ unsigned tsum[256];
    __shared__ unsigned boff_s;
    int t = threadIdx.x, b = blockIdx.x;
    int base = b * SCT + t * 16;

    if (t == 0) { unsigned o = 0; for (int i = 0; i < b; ++i) o += bsum[i]; boff_s = o; }

    unsigned v[16];
    bool full = (base + 16 <= E);
    if (full) {
        const uint4* p = (const uint4*)(h + base);
        #pragma unroll
        for (int q = 0; q < 4; ++q) { uint4 u = p[q]; v[4*q]=u.x; v[4*q+1]=u.y; v[4*q+2]=u.z; v[4*q+3]=u.w; }
    } else {
        for (int k = 0; k < 16; ++k) { int i = base + k; v[k] = (i < E) ? h[i] : 0u; }
    }
    unsigned acc = 0;
    #pragma unroll
    for (int k = 0; k < 16; ++k) { unsigned x = v[k]; v[k] = acc; acc += x; }
    tsum[t] = acc;
    __syncthreads();
    for (int off = 1; off < 256; off <<= 1) {
        unsigned u = (t >= off) ? tsum[t - off] : 0u;
        __syncthreads();
        tsum[t] += u;
        __syncthreads();
    }
    unsigned add = boff_s + ((t == 0) ? 0u : tsum[t - 1]);
    if (full) {
        uint4* p = (uint4*)(h + base);
        #pragma unroll
        for (int q = 0; q < 4; ++q)
            p[q] = make_uint4(v[4*q] + add, v[4*q+1] + add, v[4*q+2] + add, v[4*q+3] + add);
    } else {
        for (int k = 0; k < 16; ++k) { int i = base + k; if (i < E) h[i] = v[k] + add; }
    }
}

// ---------------- stable 8-bit scatter, wave-chunk layout ----------------
// Element order within tile = memory order: wave w owns [base+w*1024, base+w*1024+1024),
// iterating 16x64 (iter-major, lane-minor). Ranks: ballot rank within (wave,iter) +
// wave-running counter (earlier iters) + cross-wave prefix + tile hist base. Stable.
__global__ __launch_bounds__(256) void k_scatter8(const unsigned* __restrict__ keys,
                                                  const unsigned* __restrict__ vals, // null => identity
                                                  int N, int numTiles, int shift,
                                                  const unsigned* __restrict__ hist,
                                                  unsigned* __restrict__ okeys,      // null => skip key write
                                                  unsigned* __restrict__ ovals)
{
    __shared__ unsigned short wcnt[4][BINS];   // 2 KB
    __shared__ unsigned digStartL[BINS];       // 1 KB
    __shared__ unsigned tileBase[BINS];        // 1 KB
    __shared__ unsigned tscan[BINS];           // 1 KB
    __shared__ unsigned stage[TILE];           // 16 KB

    int t = threadIdx.x, b = blockIdx.x;
    int w = t >> 6, l = t & 63;
    int base = b * TILE;
    int nvalid = N - base; if (nvalid < 0) nvalid = 0; if (nvalid > TILE) nvalid = TILE;
    int wbase = base + w * CHUNK;

    ((unsigned*)wcnt)[t] = 0; ((unsigned*)wcnt)[256 + t] = 0;
    __syncthreads();

    unsigned k_[IPT];
    unsigned short rw_[IPT];
    unsigned char d_[IPT];

    #pragma unroll
    for (int it = 0; it < IPT; ++it) {
        int e = wbase + it * 64 + l;
        bool ok = e < N;
        unsigned kk = ok ? keys[e] : 0u;
        unsigned d = (kk >> shift) & 255u;
        unsigned long long mm = __ballot(ok);
        #pragma unroll
        for (int bb = 0; bb < 8; ++bb) {
            unsigned long long bal = __ballot(ok && ((d >> bb) & 1u));
            mm &= ((d >> bb) & 1u) ? bal : ~bal;
        }
        unsigned long long below = mm & ((1ull << l) - 1ull);
        unsigned rk = (unsigned)__popcll(below);
        unsigned before = (unsigned)wcnt[w][d];               // same-wave earlier iters
        if (ok && rk == 0)
            wcnt[w][d] = (unsigned short)(before + (unsigned)__popcll(mm));
        k_[it]  = kk;
        rw_[it] = (unsigned short)(before + rk);
        d_[it]  = (unsigned char)d;
    }
    __syncthreads();

    // cross-wave exclusive prefix per digit (thread t owns digit t) + tile totals
    {
        unsigned c0 = wcnt[0][t], c1 = wcnt[1][t], c2 = wcnt[2][t], c3 = wcnt[3][t];
        wcnt[0][t] = 0;
        wcnt[1][t] = (unsigned short)c0;
        wcnt[2][t] = (unsigned short)(c0 + c1);
        wcnt[3][t] = (unsigned short)(c0 + c1 + c2);
        tscan[t] = c0 + c1 + c2 + c3;
        tileBase[t] = hist[t * numTiles + b];
    }
    __syncthreads();
    for (int off = 1; off < 256; off <<= 1) {
        unsigned u = (t >= off) ? tscan[t - off] : 0u;
        __syncthreads();
        tscan[t] += u;
        __syncthreads();
    }
    digStartL[t] = (t == 0) ? 0u : tscan[t - 1];
    __syncthreads();

    // local positions; stage keys
    unsigned lp_[IPT];
    #pragma unroll
    for (int it = 0; it < IPT; ++it) {
        int e = wbase + it * 64 + l;
        if (e < N) {
            unsigned d = d_[it];
            lp_[it] = digStartL[d] + (unsigned)wcnt[w][d] + (unsigned)rw_[it];
            stage[lp_[it]] = k_[it];
        }
    }
    __syncthreads();

    // coalesced key write-out; capture global positions per linear slot
    unsigned pos_[IPT];
    #pragma unroll
    for (int it = 0; it < IPT; ++it) {
        int p = it * BLK + t;
        if (p < nvalid) {
            unsigned kk = stage[p];
            unsigned d = (kk >> shift) & 255u;
            unsigned pos = tileBase[d] + ((unsigned)p - digStartL[d]);
            pos_[it] = pos;
            if (okeys) okeys[pos] = kk;
        }
    }
    __syncthreads();

    // stage vals (identity on pass 0), coalesced write-out
    #pragma unroll
    for (int it = 0; it < IPT; ++it) {
        int e = wbase + it * 64 + l;
        if (e < N) stage[lp_[it]] = vals ? vals[e] : (unsigned)e;
    }
    __syncthreads();
    #pragma unroll
    for (int it = 0; it < IPT; ++it) {
        int p = it * BLK + t;
        if (p < nvalid) ovals[pos_[it]] = stage[p];
    }
}

// ---------------- permute 64B rows -> compact 21-float sorted output ----------------
__global__ __launch_bounds__(256) void k_perm(const unsigned* __restrict__ order,
                                              const float* __restrict__ rows,
                                              float* __restrict__ out, int N)
{
    __shared__ float srow[256 * 21];
    int i = blockIdx.x * 256 + threadIdx.x;
    if (i < N) {
        int j = (int)order[i];
        const float4* rp = (const float4*)(rows + (size_t)j * 16);
        float4 a = rp[0], b4 = rp[1], c4 = rp[2], d4 = rp[3];
        float px = a.x,  py = a.y,  zv = a.z,  c00 = a.w;
        float c01 = b4.x, c11 = b4.y, i00 = b4.z, i01 = b4.w;
        float i11 = c4.x, rad = c4.y, cr = c4.z, cg = c4.w;
        float cb = d4.x,  op = d4.y,  iv = d4.z;
        float* r = &srow[threadIdx.x * 21];
        r[0]=px; r[1]=py; r[2]=zv;
        r[3]=c00; r[4]=c01; r[5]=c01; r[6]=c11;        // c10 == c01 (symmetric, ~ulp)
        r[7]=i00; r[8]=i01; r[9]=i01; r[10]=i11;       // i10 == i01
        r[11]=rad;
        r[12]=floorf(px - rad); r[13]=floorf(py - rad);
        r[14]=ceilf(px + rad);  r[15]=ceilf(py + rad);
        r[16]=cr; r[17]=cg; r[18]=cb;
        r[19]=op; r[20]=iv;
    }
    __syncthreads();
    int blockBase = blockIdx.x * 256;
    int valid = N - blockBase; if (valid > 256) valid = 256;
    if (valid > 0) {
        float* dst = out + (size_t)blockBase * 21;
        for (int u = threadIdx.x; u < valid * 21; u += 256) dst[u] = srow[u];
    }
}

extern "C" void kernel_launch(void* const* d_in, const int* in_sizes, int n_in,
                              void* d_out, int out_size, void* d_ws, size_t ws_size,
                              hipStream_t stream)
{
    const float* pts  = (const float*)d_in[0];
    const float* cols = (const float*)d_in[1];
    const float* opa  = (const float*)d_in[2];
    const float* scl  = (const float*)d_in[3];
    const float* qt   = (const float*)d_in[4];
    const float* w2v  = (const float*)d_in[5];
    const float* fpm  = (const float*)d_in[6];
    const float* tanx = (const float*)d_in[7];
    const float* tany = (const float*)d_in[8];
    const float* fx   = (const float*)d_in[9];
    const float* fy   = (const float*)d_in[10];
    const int*   wp   = (const int*)d_in[11];
    const int*   hp   = (const int*)d_in[12];

    int N = in_sizes[0] / 3;
    int numTiles = (N + TILE - 1) / TILE;
    int nb = (N + 255) / 256;
    int E = BINS * numTiles;
    int nScan = (E + SCT - 1) / SCT;

    unsigned* kA   = (unsigned*)d_ws;
    unsigned* kB   = kA + N;
    unsigned* vA   = kB + N;
    unsigned* vB   = vA + N;
    unsigned* hist = vB + N;                   // E entries
    unsigned* bsum = hist + E;                 // nScan entries
    float*    rows = (float*)(bsum + nScan);   // 16*N floats

    // rows + keys in one pass over the inputs
    k_rows<<<nb, 256, 0, stream>>>(pts, cols, opa, scl, qt, w2v, fpm,
                                   tanx, tany, fx, fy, wp, hp, rows, kA, N);

    // pass 0: kA (identity vals) -> kB, vA
    k_hist8<<<numTiles, 256, 0, stream>>>(kA, N, numTiles, 0, hist);
    k_scanA<<<nScan, 256, 0, stream>>>(hist, E, bsum);
    k_scanB<<<nScan, 256, 0, stream>>>(hist, E, bsum);
    k_scatter8<<<numTiles, 256, 0, stream>>>(kA, nullptr, N, numTiles, 0, hist, kB, vA);

    // pass 1: kB, vA -> kA, vB
    k_hist8<<<numTiles, 256, 0, stream>>>(kB, N, numTiles, 8, hist);
    k_scanA<<<nScan, 256, 0, stream>>>(hist, E, bsum);
    k_scanB<<<nScan, 256, 0, stream>>>(hist, E, bsum);
    k_scatter8<<<numTiles, 256, 0, stream>>>(kB, vA, N, numTiles, 8, hist, kA, vB);

    // pass 2: kA, vB -> kB, vA
    k_hist8<<<numTiles, 256, 0, stream>>>(kA, N, numTiles, 16, hist);
    k_scanA<<<nScan, 256, 0, stream>>>(hist, E, bsum);
    k_scanB<<<nScan, 256, 0, stream>>>(hist, E, bsum);
    k_scatter8<<<numTiles, 256, 0, stream>>>(kA, vB, N, numTiles, 16, hist, kB, vA);

    // pass 3: kB, vA -> vB only (keys no longer needed)
    k_hist8<<<numTiles, 256, 0, stream>>>(kB, N, numTiles, 24, hist);
    k_scanA<<<nScan, 256, 0, stream>>>(hist, E, bsum);
    k_scanB<<<nScan, 256, 0, stream>>>(hist, E, bsum);
    k_scatter8<<<numTiles, 256, 0, stream>>>(kB, vA, N, numTiles, 24, hist, nullptr, vB);

    // gather rows in sorted order
    k_perm<<<nb, 256, 0, stream>>>(vB, rows, (float*)d_out, N);
}